// Round 1
// baseline (5572.881 us; speedup 1.0000x reference)
//
#include <hip/hip_runtime.h>

#define FIN 256
#define KNN 50
#define JB  2000

static __device__ __forceinline__ float lrelu02(float v){ return v > 0.f ? v : 0.2f*v; }

// ---------------- CSR construction ----------------
__global__ __launch_bounds__(256) void k_zero_int(int* p, int n){
  int i = blockIdx.x*256 + threadIdx.x; if (i<n) p[i]=0;
}
__global__ __launch_bounds__(256) void k_count_deg(const int* __restrict__ dstv, int* deg, int E){
  int i = blockIdx.x*256 + threadIdx.x; if (i<E) atomicAdd(&deg[dstv[i]], 1);
}
__global__ __launch_bounds__(256) void k_scan(const int* __restrict__ deg, int* offs, int* cursor, int n){
  __shared__ int buf[256]; __shared__ int carry;
  int t = threadIdx.x;
  if (t==0) carry = 0;
  __syncthreads();
  for (int base=0; base<n; base+=256){
    int v = (base+t<n)? deg[base+t] : 0;
    buf[t]=v; __syncthreads();
    for (int off=1; off<256; off<<=1){
      int add = (t>=off)? buf[t-off] : 0;
      __syncthreads();
      buf[t]+=add; __syncthreads();
    }
    int excl = buf[t]-v+carry;
    if (base+t<n){ offs[base+t]=excl; cursor[base+t]=excl; }
    __syncthreads();
    if (t==0) carry += buf[255];
    __syncthreads();
  }
}
__global__ __launch_bounds__(256) void k_fill_csr(const int* __restrict__ dstv, int* cursor, int* csr, int E){
  int i = blockIdx.x*256 + threadIdx.x;
  if (i<E){ int p=atomicAdd(&cursor[dstv[i]],1); csr[p]=i; }
}
// deterministic aggregation order: sort each node's edge list ascending by edge id
__global__ __launch_bounds__(256) void k_sort_csr(int* csr, const int* __restrict__ offs, const int* __restrict__ deg, int n){
  int i = blockIdx.x*256+threadIdx.x; if (i>=n) return;
  int st=offs[i], d=deg[i];
  for (int a=0;a<d-1;++a){
    int mv=csr[st+a], mp=a;
    for (int b=a+1;b<d;++b){ int v=csr[st+b]; if (v<mv){mv=v;mp=b;} }
    int tmp=csr[st+a]; csr[st+a]=mv; csr[st+mp]=tmp;
  }
}

// ---------------- generic fp32 GEMM: C = act(A * W^T + b) ----------------
// A: [M x >=K] row-major lda, W: [O x K] row-major ldw, C row-major ldc with column offset
__global__ __launch_bounds__(256) void gemm_bt(
    const float* __restrict__ A, int lda,
    const float* __restrict__ W, int ldw,
    const float* __restrict__ bias,
    float* __restrict__ C, int ldc, int coff,
    int M, int Kdim, int O, int relu)
{
  __shared__ float As[32][68];
  __shared__ float Ws[32][68];
  int t  = threadIdx.x;
  int n0 = blockIdx.y * 64;
  int o0 = blockIdx.x * 64;
  int tx = t & 15, ty = t >> 4;
  float acc[4][4] = {};
  int kgrp = t & 7;      // k = 4*kgrp
  int row  = t >> 3;     // 0..31
  for (int k0 = 0; k0 < Kdim; k0 += 32) {
    #pragma unroll
    for (int p = 0; p < 2; ++p) {
      int r = row + 32*p;
      int n = n0 + r;
      float4 v = make_float4(0.f,0.f,0.f,0.f);
      if (n < M) v = *(const float4*)(A + (size_t)n*lda + k0 + 4*kgrp);
      As[4*kgrp+0][r] = v.x; As[4*kgrp+1][r] = v.y;
      As[4*kgrp+2][r] = v.z; As[4*kgrp+3][r] = v.w;
      int o = o0 + r;
      float4 w = make_float4(0.f,0.f,0.f,0.f);
      if (o < O) w = *(const float4*)(W + (size_t)o*ldw + k0 + 4*kgrp);
      Ws[4*kgrp+0][r] = w.x; Ws[4*kgrp+1][r] = w.y;
      Ws[4*kgrp+2][r] = w.z; Ws[4*kgrp+3][r] = w.w;
    }
    __syncthreads();
    #pragma unroll 8
    for (int kk = 0; kk < 32; ++kk) {
      float4 a = *(const float4*)&As[kk][ty*4];
      float4 w = *(const float4*)&Ws[kk][tx*4];
      float av[4] = {a.x,a.y,a.z,a.w};
      float wv[4] = {w.x,w.y,w.z,w.w};
      #pragma unroll
      for (int i=0;i<4;++i)
        #pragma unroll
        for (int j=0;j<4;++j) acc[i][j] += av[i]*wv[j];
    }
    __syncthreads();
  }
  #pragma unroll
  for (int i=0;i<4;++i) {
    int n = n0 + ty*4 + i;
    if (n >= M) continue;
    #pragma unroll
    for (int j=0;j<4;++j) {
      int o = o0 + tx*4 + j;
      if (o >= O) continue;
      float v = acc[i][j] + (bias ? bias[o] : 0.f);
      if (relu) v = fmaxf(v, 0.f);
      C[(size_t)n*ldc + coff + o] = v;
    }
  }
}

// ---------------- attention logits: al[n][h] = <h[n,h,:], a[h,:]> ----------------
__global__ __launch_bounds__(256) void att_logits(
    const float* __restrict__ hbuf, const float* __restrict__ asrc,
    const float* __restrict__ adst, float* __restrict__ als, float* __restrict__ ald,
    int H, int M)
{
  int gidx = blockIdx.x*256 + threadIdx.x;
  if (gidx >= M*H) return;
  int n = gidx / H, h = gidx % H;
  const float* hp = hbuf + (size_t)n*H*128 + (size_t)h*128;
  const float* as = asrc + h*128;
  const float* ad = adst + h*128;
  float s1=0.f, s2=0.f;
  for (int c=0;c<128;++c){ float v=hp[c]; s1 += v*as[c]; s2 += v*ad[c]; }
  als[gidx]=s1; ald[gidx]=s2;
}

// ---------------- GAT softmax-aggregation (deterministic, CSR per dst node) -----
template<int H, int OUT, int RELU>
__global__ __launch_bounds__(256) void gat_aggregate(
  const float* __restrict__ hbuf, const float* __restrict__ als, const float* __restrict__ ald,
  const int* __restrict__ csr, const int* __restrict__ offs, const int* __restrict__ deg,
  const int* __restrict__ srcv, const float* __restrict__ bias,
  float* __restrict__ outp, int ldo, int coff, int M)
{
  int n = blockIdx.x; int t = threadIdx.x;
  int d = deg[n], st = offs[n];
  __shared__ float red[256];
  __shared__ float emax[H], dsum[H];
  // phase 1: per-head max of leaky_relu(al_src[s]+al_dst[n])
  float lm[H];
  #pragma unroll
  for (int h=0;h<H;++h) lm[h] = -__builtin_inff();
  for (int q=t;q<d;q+=256) {
    int eid = csr[st+q]; int s = srcv[eid];
    #pragma unroll
    for (int h=0;h<H;++h) {
      float v = lrelu02(als[s*H+h] + ald[n*H+h]);
      lm[h] = fmaxf(lm[h], v);
    }
  }
  #pragma unroll
  for (int h=0;h<H;++h) {
    red[t]=lm[h]; __syncthreads();
    for (int s2=128;s2>0;s2>>=1){ if(t<s2) red[t]=fmaxf(red[t],red[t+s2]); __syncthreads(); }
    if (t==0) emax[h]=red[0];
    __syncthreads();
  }
  // phase 2: denom = sum exp(e - emax) + 1e-16
  float ls[H];
  #pragma unroll
  for (int h=0;h<H;++h) ls[h]=0.f;
  for (int q=t;q<d;q+=256) {
    int eid = csr[st+q]; int s = srcv[eid];
    #pragma unroll
    for (int h=0;h<H;++h) {
      float v = lrelu02(als[s*H+h] + ald[n*H+h]);
      ls[h] += expf(v - emax[h]);
    }
  }
  #pragma unroll
  for (int h=0;h<H;++h) {
    red[t]=ls[h]; __syncthreads();
    for (int s2=128;s2>0;s2>>=1){ if(t<s2) red[t]+=red[t+s2]; __syncthreads(); }
    if (t==0) dsum[h]=red[0] + 1e-16f;
    __syncthreads();
  }
  // phase 3: out[n, base..base+3] = sum_e alpha * h[s, base..base+3]
  int base = t*4;
  if (base < OUT) {
    const int h = base >> 7;  // /128
    float a0=0.f,a1=0.f,a2=0.f,a3=0.f;
    float em = emax[h], dn = dsum[h];
    float aldnh = ald[n*H+h];
    for (int q=0;q<d;++q) {
      int eid=csr[st+q]; int s=srcv[eid];
      float v = lrelu02(als[s*H+h] + aldnh);
      float alpha = expf(v-em)/dn;
      float4 hv = *(const float4*)(hbuf + (size_t)s*OUT + base);
      a0 += hv.x*alpha; a1 += hv.y*alpha; a2 += hv.z*alpha; a3 += hv.w*alpha;
    }
    a0 += bias[base+0]; a1 += bias[base+1]; a2 += bias[base+2]; a3 += bias[base+3];
    if (RELU){ a0=fmaxf(a0,0.f); a1=fmaxf(a1,0.f); a2=fmaxf(a2,0.f); a3=fmaxf(a3,0.f); }
    float* op = outp + (size_t)n*ldo + coff + base;
    op[0]=a0; op[1]=a1; op[2]=a2; op[3]=a3;
  }
}

// ---------------- knn: sq norms ----------------
__global__ __launch_bounds__(256) void k_sq(const float* __restrict__ g, float* sq, int n){
  int i = blockIdx.x*256+threadIdx.x;
  if (i<n){ const float* p=g+(size_t)i*64; float s=0.f; for(int c=0;c<64;++c) s+=p[c]*p[c]; sq[i]=s; }
}
__global__ __launch_bounds__(256) void k_init_topk(float* tv, int* ti, int n){
  int i = blockIdx.x*256+threadIdx.x;
  if (i<n){ tv[i]=-__builtin_inff(); ti[i]=0; }
}

// ---------------- gram slab: neg_d2 = 2*(g_i . g_j) - sq_i - sq_j ----------------
__global__ __launch_bounds__(256) void gram_negd2(
    const float* __restrict__ G, const float* __restrict__ sqv,
    float* __restrict__ slab, int j0, int M)
{
  __shared__ float Gi[64][68];
  __shared__ float Gj[64][68];
  int t = threadIdx.x;
  int i0  = blockIdx.y * 64;
  int jt0 = blockIdx.x * 64;   // local j within slab
  int tx = t & 15, ty = t >> 4;
  int kg  = t & 15;   // k = 4*kg
  int row = t >> 4;   // 0..15
  #pragma unroll
  for (int p=0;p<4;++p) {
    int r = row + 16*p;
    int i = i0 + r;
    float4 v = make_float4(0.f,0.f,0.f,0.f);
    if (i < M) v = *(const float4*)(G + (size_t)i*64 + 4*kg);
    Gi[4*kg+0][r]=v.x; Gi[4*kg+1][r]=v.y; Gi[4*kg+2][r]=v.z; Gi[4*kg+3][r]=v.w;
    int j = j0 + jt0 + r;
    float4 w = make_float4(0.f,0.f,0.f,0.f);
    if (j < M) w = *(const float4*)(G + (size_t)j*64 + 4*kg);
    Gj[4*kg+0][r]=w.x; Gj[4*kg+1][r]=w.y; Gj[4*kg+2][r]=w.z; Gj[4*kg+3][r]=w.w;
  }
  __syncthreads();
  float acc[4][4] = {};
  #pragma unroll 8
  for (int kk=0;kk<64;++kk) {
    float4 a = *(const float4*)&Gi[kk][ty*4];
    float4 b = *(const float4*)&Gj[kk][tx*4];
    float av[4]={a.x,a.y,a.z,a.w};
    float bv[4]={b.x,b.y,b.z,b.w};
    #pragma unroll
    for (int i=0;i<4;++i)
      #pragma unroll
      for (int j=0;j<4;++j) acc[i][j] += av[i]*bv[j];
  }
  #pragma unroll
  for (int i=0;i<4;++i){
    int ii = i0 + ty*4 + i;
    if (ii >= M) continue;
    #pragma unroll
    for (int j=0;j<4;++j){
      int jl = jt0 + tx*4 + j;
      int jg = j0 + jl;
      if (jl < JB && jg < M)
        slab[(size_t)ii*JB + jl] = 2.f*acc[i][j] - sqv[ii] - sqv[jg];
    }
  }
}

// ---------------- per-row running top-50 merge over a slab ----------------
__global__ __launch_bounds__(256) void topk_merge(
    const float* __restrict__ slab, int j0, int jcount,
    float* __restrict__ topv, int* __restrict__ topi, int M)
{
  __shared__ float vals[JB + KNN];
  __shared__ int   oldidx[KNN];
  __shared__ float rv[256];
  __shared__ int   rp[256];
  __shared__ float nv[KNN];
  __shared__ int   ni[KNN];
  int i = blockIdx.x; int t = threadIdx.x;
  for (int p=t;p<jcount;p+=256) vals[p] = slab[(size_t)i*JB + p];
  for (int p=jcount+t; p<JB; p+=256) vals[p] = -__builtin_inff();
  if (t < KNN) { vals[JB+t] = topv[(size_t)i*KNN+t]; oldidx[t] = topi[(size_t)i*KNN+t]; }
  __syncthreads();
  const int total = JB + KNN;
  for (int it=0; it<KNN; ++it) {
    float bv = -__builtin_inff(); int bp = -1; int bidx = 0x7fffffff;
    for (int p=t; p<total; p+=256) {
      float v = vals[p];
      int idx = (p < JB) ? (j0 + p) : oldidx[p-JB];
      if (v > bv || (v == bv && idx < bidx)) { bv=v; bp=p; bidx=idx; }
    }
    rv[t]=bv; rp[t]=bp; __syncthreads();
    for (int s=128; s>0; s>>=1) {
      if (t < s) {
        float v1 = rv[t];   int p1 = rp[t];
        float v2 = rv[t+s]; int p2 = rp[t+s];
        int i1 = (p1<0)?0x7fffffff:((p1<JB)?(j0+p1):oldidx[p1-JB]);
        int i2 = (p2<0)?0x7fffffff:((p2<JB)?(j0+p2):oldidx[p2-JB]);
        if (v2 > v1 || (v2 == v1 && i2 < i1)) { rv[t]=v2; rp[t]=p2; }
      }
      __syncthreads();
    }
    if (t==0) {
      int p = rp[0];
      nv[it] = rv[0];
      ni[it] = (p<JB)?(j0+p):oldidx[p-JB];
      vals[p] = -__builtin_inff();
    }
    __syncthreads();
  }
  if (t < KNN) { topv[(size_t)i*KNN+t]=nv[t]; topi[(size_t)i*KNN+t]=ni[t]; }
}

// ---------------- gather-mean over top-50 + LayerNorm, writes cat[:,256:512] ----
__global__ __launch_bounds__(256) void knn_mean_ln(
    float* __restrict__ cat, const int* __restrict__ topi,
    const float* __restrict__ g, const float* __restrict__ b, int M)
{
  int i = blockIdx.x; int t = threadIdx.x;
  __shared__ int idx[KNN];
  __shared__ float red[256];
  if (t<KNN) idx[t]=topi[(size_t)i*KNN+t];
  __syncthreads();
  float acc=0.f;
  for (int r=0;r<KNN;++r) acc += cat[(size_t)idx[r]*512 + t];
  float xval = acc * (1.f/KNN);
  red[t]=xval; __syncthreads();
  for (int s=128;s>0;s>>=1){ if(t<s) red[t]+=red[t+s]; __syncthreads(); }
  float mu = red[0]*(1.f/256.f); __syncthreads();
  float d = xval-mu;
  red[t]=d*d; __syncthreads();
  for (int s=128;s>0;s>>=1){ if(t<s) red[t]+=red[t+s]; __syncthreads(); }
  float var = red[0]*(1.f/256.f);
  float y = d * rsqrtf(var+1e-5f) * g[t] + b[t];
  cat[(size_t)i*512 + 256 + t] = y;
}

// ================================================================
extern "C" void kernel_launch(void* const* d_in, const int* in_sizes, int n_in,
                              void* d_out, int out_size, void* d_ws, size_t ws_size,
                              hipStream_t stream)
{
  const float* x      = (const float*)d_in[0];
  const int*   ei     = (const int*)  d_in[1];
  const float* lin1_w = (const float*)d_in[2];
  const float* lin1_b = (const float*)d_in[3];
  const float* gat1_w = (const float*)d_in[4];
  const float* g1_as  = (const float*)d_in[5];
  const float* g1_ad  = (const float*)d_in[6];
  const float* gat1_b = (const float*)d_in[7];
  const float* gat2_w = (const float*)d_in[8];
  const float* g2_as  = (const float*)d_in[9];
  const float* g2_ad  = (const float*)d_in[10];
  const float* gat2_b = (const float*)d_in[11];
  const float* proj_w = (const float*)d_in[12];
  const float* proj_b = (const float*)d_in[13];
  const float* ln_g   = (const float*)d_in[14];
  const float* ln_b   = (const float*)d_in[15];
  const float* lin_w  = (const float*)d_in[16];
  const float* lin_b  = (const float*)d_in[17];
  float* outp = (float*)d_out;

  const int N = in_sizes[0]/FIN;    // 10000
  const int E = in_sizes[1]/2;      // 320000
  const int* srcv = ei;
  const int* dstv = ei + E;

  float* ws = (float*)d_ws;
  size_t f = 0;
  float* h1   = ws + f; f += (size_t)N*1024;
  float* xg   = ws + f; f += (size_t)N*1024;
  float* slab = h1;                       // overlays h1+xg (dead by knn time): N*JB <= N*2048
  float* cat  = ws + f; f += (size_t)N*512;
  float* al1s = ws + f; f += (size_t)N*8;
  float* al1d = ws + f; f += (size_t)N*8;
  float* h2   = ws + f; f += (size_t)N*128;
  float* al2s = ws + f; f += (size_t)N;
  float* al2d = ws + f; f += (size_t)N;
  float* gsc  = ws + f; f += (size_t)N*64;
  float* sqv  = ws + f; f += (size_t)N;
  float* topv = ws + f; f += (size_t)N*KNN;
  int* topi   = (int*)(ws + f); f += (size_t)N*KNN;
  int* deg    = (int*)(ws + f); f += (size_t)N;
  int* offs   = (int*)(ws + f); f += (size_t)N;
  int* cursor = (int*)(ws + f); f += (size_t)N;
  int* csr    = (int*)(ws + f); f += (size_t)E;
  (void)ws_size; (void)n_in; (void)out_size;

  dim3 b256(256);
  int gy = (N+63)/64;

  // CSR by dst
  k_zero_int<<<(N+255)/256, b256, 0, stream>>>(deg, N);
  k_count_deg<<<(E+255)/256, b256, 0, stream>>>(dstv, deg, E);
  k_scan<<<1, b256, 0, stream>>>(deg, offs, cursor, N);
  k_fill_csr<<<(E+255)/256, b256, 0, stream>>>(dstv, cursor, csr, E);
  k_sort_csr<<<(N+255)/256, b256, 0, stream>>>(csr, offs, deg, N);

  // x1 = relu(x@lin1_w.T + b) -> cat[:, :128]
  gemm_bt<<<dim3(2,gy), b256, 0, stream>>>(x,FIN, lin1_w,FIN, lin1_b, cat,512,0, N,FIN,128, 1);
  // h1 = x @ gat1_w.T
  gemm_bt<<<dim3(16,gy), b256, 0, stream>>>(x,FIN, gat1_w,FIN, nullptr, h1,1024,0, N,FIN,1024, 0);
  att_logits<<<(N*8+255)/256, b256, 0, stream>>>(h1, g1_as, g1_ad, al1s, al1d, 8, N);
  gat_aggregate<8,1024,1><<<N, b256, 0, stream>>>(h1, al1s, al1d, csr, offs, deg, srcv, gat1_b, xg,1024,0, N);
  // h2 = xg @ gat2_w.T
  gemm_bt<<<dim3(2,gy), b256, 0, stream>>>(xg,1024, gat2_w,1024, nullptr, h2,128,0, N,1024,128, 0);
  att_logits<<<(N+255)/256, b256, 0, stream>>>(h2, g2_as, g2_ad, al2s, al2d, 1, N);
  gat_aggregate<1,128,0><<<N, b256, 0, stream>>>(h2, al2s, al2d, csr, offs, deg, srcv, gat2_b, cat,512,128, N);
  // g_score = final @ proj_w.T + proj_b
  gemm_bt<<<dim3(1,gy), b256, 0, stream>>>(cat,512, proj_w,256, proj_b, gsc,64,0, N,256,64, 0);
  k_sq<<<(N+255)/256, b256, 0, stream>>>(gsc, sqv, N);
  k_init_topk<<<(N*KNN+255)/256, b256, 0, stream>>>(topv, topi, N*KNN);
  // knn: 5 slabs of 2000 columns; gram then running top-50 merge
  for (int j0=0; j0<N; j0+=JB){
    int jc = (N - j0 < JB) ? (N - j0) : JB;
    gram_negd2<<<dim3((JB+63)/64, gy), b256, 0, stream>>>(gsc, sqv, slab, j0, N);
    topk_merge<<<N, b256, 0, stream>>>(slab, j0, jc, topv, topi, N);
  }
  knn_mean_ln<<<N, b256, 0, stream>>>(cat, topi, ln_g, ln_b, N);
  // out = [final, sim] @ lin_w.T + lin_b
  gemm_bt<<<dim3(1,gy), b256, 0, stream>>>(cat,512, lin_w,512, lin_b, outp,64,0, N,512,64, 0);
}

// Round 2
// 1730.272 us; speedup vs baseline: 3.2208x; 3.2208x over previous
//
#include <hip/hip_runtime.h>

#define FIN 256
#define KNN 50
#define JB  2000

static __device__ __forceinline__ float lrelu02(float v){ return v > 0.f ? v : 0.2f*v; }

// ---------------- CSR construction ----------------
__global__ __launch_bounds__(256) void k_zero_int(int* p, int n){
  int i = blockIdx.x*256 + threadIdx.x; if (i<n) p[i]=0;
}
__global__ __launch_bounds__(256) void k_count_deg(const int* __restrict__ dstv, int* deg, int E){
  int i = blockIdx.x*256 + threadIdx.x; if (i<E) atomicAdd(&deg[dstv[i]], 1);
}
__global__ __launch_bounds__(256) void k_scan(const int* __restrict__ deg, int* offs, int* cursor, int n){
  __shared__ int buf[256]; __shared__ int carry;
  int t = threadIdx.x;
  if (t==0) carry = 0;
  __syncthreads();
  for (int base=0; base<n; base+=256){
    int v = (base+t<n)? deg[base+t] : 0;
    buf[t]=v; __syncthreads();
    for (int off=1; off<256; off<<=1){
      int add = (t>=off)? buf[t-off] : 0;
      __syncthreads();
      buf[t]+=add; __syncthreads();
    }
    int excl = buf[t]-v+carry;
    if (base+t<n){ offs[base+t]=excl; cursor[base+t]=excl; }
    __syncthreads();
    if (t==0) carry += buf[255];
    __syncthreads();
  }
}
__global__ __launch_bounds__(256) void k_fill_csr(const int* __restrict__ dstv, int* cursor, int* csr, int E){
  int i = blockIdx.x*256 + threadIdx.x;
  if (i<E){ int p=atomicAdd(&cursor[dstv[i]],1); csr[p]=i; }
}
// deterministic aggregation order: sort each node's edge list ascending by edge id
__global__ __launch_bounds__(256) void k_sort_csr(int* csr, const int* __restrict__ offs, const int* __restrict__ deg, int n){
  int i = blockIdx.x*256+threadIdx.x; if (i>=n) return;
  int st=offs[i], d=deg[i];
  for (int a=0;a<d-1;++a){
    int mv=csr[st+a], mp=a;
    for (int b=a+1;b<d;++b){ int v=csr[st+b]; if (v<mv){mv=v;mp=b;} }
    int tmp=csr[st+a]; csr[st+a]=mv; csr[st+mp]=tmp;
  }
}

// ---------------- generic fp32 GEMM: C = act(A * W^T + b) ----------------
__global__ __launch_bounds__(256) void gemm_bt(
    const float* __restrict__ A, int lda,
    const float* __restrict__ W, int ldw,
    const float* __restrict__ bias,
    float* __restrict__ C, int ldc, int coff,
    int M, int Kdim, int O, int relu)
{
  __shared__ float As[32][68];
  __shared__ float Ws[32][68];
  int t  = threadIdx.x;
  int n0 = blockIdx.y * 64;
  int o0 = blockIdx.x * 64;
  int tx = t & 15, ty = t >> 4;
  float acc[4][4] = {};
  int kgrp = t & 7;      // k = 4*kgrp
  int row  = t >> 3;     // 0..31
  for (int k0 = 0; k0 < Kdim; k0 += 32) {
    #pragma unroll
    for (int p = 0; p < 2; ++p) {
      int r = row + 32*p;
      int n = n0 + r;
      float4 v = make_float4(0.f,0.f,0.f,0.f);
      if (n < M) v = *(const float4*)(A + (size_t)n*lda + k0 + 4*kgrp);
      As[4*kgrp+0][r] = v.x; As[4*kgrp+1][r] = v.y;
      As[4*kgrp+2][r] = v.z; As[4*kgrp+3][r] = v.w;
      int o = o0 + r;
      float4 w = make_float4(0.f,0.f,0.f,0.f);
      if (o < O) w = *(const float4*)(W + (size_t)o*ldw + k0 + 4*kgrp);
      Ws[4*kgrp+0][r] = w.x; Ws[4*kgrp+1][r] = w.y;
      Ws[4*kgrp+2][r] = w.z; Ws[4*kgrp+3][r] = w.w;
    }
    __syncthreads();
    #pragma unroll 8
    for (int kk = 0; kk < 32; ++kk) {
      float4 a = *(const float4*)&As[kk][ty*4];
      float4 w = *(const float4*)&Ws[kk][tx*4];
      float av[4] = {a.x,a.y,a.z,a.w};
      float wv[4] = {w.x,w.y,w.z,w.w};
      #pragma unroll
      for (int i=0;i<4;++i)
        #pragma unroll
        for (int j=0;j<4;++j) acc[i][j] += av[i]*wv[j];
    }
    __syncthreads();
  }
  #pragma unroll
  for (int i=0;i<4;++i) {
    int n = n0 + ty*4 + i;
    if (n >= M) continue;
    #pragma unroll
    for (int j=0;j<4;++j) {
      int o = o0 + tx*4 + j;
      if (o >= O) continue;
      float v = acc[i][j] + (bias ? bias[o] : 0.f);
      if (relu) v = fmaxf(v, 0.f);
      C[(size_t)n*ldc + coff + o] = v;
    }
  }
}

// ---------------- attention logits ----------------
__global__ __launch_bounds__(256) void att_logits(
    const float* __restrict__ hbuf, const float* __restrict__ asrc,
    const float* __restrict__ adst, float* __restrict__ als, float* __restrict__ ald,
    int H, int M)
{
  int gidx = blockIdx.x*256 + threadIdx.x;
  if (gidx >= M*H) return;
  int n = gidx / H, h = gidx % H;
  const float* hp = hbuf + (size_t)n*H*128 + (size_t)h*128;
  const float* as = asrc + h*128;
  const float* ad = adst + h*128;
  float s1=0.f, s2=0.f;
  for (int c=0;c<128;++c){ float v=hp[c]; s1 += v*as[c]; s2 += v*ad[c]; }
  als[gidx]=s1; ald[gidx]=s2;
}

// ---------------- GAT softmax-aggregation (deterministic, CSR per dst node) -----
template<int H, int OUT, int RELU>
__global__ __launch_bounds__(256) void gat_aggregate(
  const float* __restrict__ hbuf, const float* __restrict__ als, const float* __restrict__ ald,
  const int* __restrict__ csr, const int* __restrict__ offs, const int* __restrict__ deg,
  const int* __restrict__ srcv, const float* __restrict__ bias,
  float* __restrict__ outp, int ldo, int coff, int M)
{
  int n = blockIdx.x; int t = threadIdx.x;
  int d = deg[n], st = offs[n];
  __shared__ float red[256];
  __shared__ float emax[H], dsum[H];
  float lm[H];
  #pragma unroll
  for (int h=0;h<H;++h) lm[h] = -__builtin_inff();
  for (int q=t;q<d;q+=256) {
    int eid = csr[st+q]; int s = srcv[eid];
    #pragma unroll
    for (int h=0;h<H;++h) {
      float v = lrelu02(als[s*H+h] + ald[n*H+h]);
      lm[h] = fmaxf(lm[h], v);
    }
  }
  #pragma unroll
  for (int h=0;h<H;++h) {
    red[t]=lm[h]; __syncthreads();
    for (int s2=128;s2>0;s2>>=1){ if(t<s2) red[t]=fmaxf(red[t],red[t+s2]); __syncthreads(); }
    if (t==0) emax[h]=red[0];
    __syncthreads();
  }
  float ls[H];
  #pragma unroll
  for (int h=0;h<H;++h) ls[h]=0.f;
  for (int q=t;q<d;q+=256) {
    int eid = csr[st+q]; int s = srcv[eid];
    #pragma unroll
    for (int h=0;h<H;++h) {
      float v = lrelu02(als[s*H+h] + ald[n*H+h]);
      ls[h] += expf(v - emax[h]);
    }
  }
  #pragma unroll
  for (int h=0;h<H;++h) {
    red[t]=ls[h]; __syncthreads();
    for (int s2=128;s2>0;s2>>=1){ if(t<s2) red[t]+=red[t+s2]; __syncthreads(); }
    if (t==0) dsum[h]=red[0] + 1e-16f;
    __syncthreads();
  }
  int base = t*4;
  if (base < OUT) {
    const int h = base >> 7;
    float a0=0.f,a1=0.f,a2=0.f,a3=0.f;
    float em = emax[h], dn = dsum[h];
    float aldnh = ald[n*H+h];
    for (int q=0;q<d;++q) {
      int eid=csr[st+q]; int s=srcv[eid];
      float v = lrelu02(als[s*H+h] + aldnh);
      float alpha = expf(v-em)/dn;
      float4 hv = *(const float4*)(hbuf + (size_t)s*OUT + base);
      a0 += hv.x*alpha; a1 += hv.y*alpha; a2 += hv.z*alpha; a3 += hv.w*alpha;
    }
    a0 += bias[base+0]; a1 += bias[base+1]; a2 += bias[base+2]; a3 += bias[base+3];
    if (RELU){ a0=fmaxf(a0,0.f); a1=fmaxf(a1,0.f); a2=fmaxf(a2,0.f); a3=fmaxf(a3,0.f); }
    float* op = outp + (size_t)n*ldo + coff + base;
    op[0]=a0; op[1]=a1; op[2]=a2; op[3]=a3;
  }
}

// ---------------- knn: sq norms ----------------
__global__ __launch_bounds__(256) void k_sq(const float* __restrict__ g, float* sq, int n){
  int i = blockIdx.x*256+threadIdx.x;
  if (i<n){ const float* p=g+(size_t)i*64; float s=0.f; for(int c=0;c<64;++c) s+=p[c]*p[c]; sq[i]=s; }
}
// init running top-k: key 0 (below any real mapped float), idx = +inf sentinel
__global__ __launch_bounds__(256) void k_init_topk(unsigned int* tk, int* ti, int n){
  int i = blockIdx.x*256+threadIdx.x;
  if (i<n){ tk[i]=0u; ti[i]=0x7fffffff; }
}

// ---------------- gram slab: neg_d2 = 2*(g_i . g_j) - sq_i - sq_j ----------------
__global__ __launch_bounds__(256) void gram_negd2(
    const float* __restrict__ G, const float* __restrict__ sqv,
    float* __restrict__ slab, int j0, int M)
{
  __shared__ float Gi[64][68];
  __shared__ float Gj[64][68];
  int t = threadIdx.x;
  int i0  = blockIdx.y * 64;
  int jt0 = blockIdx.x * 64;
  int tx = t & 15, ty = t >> 4;
  int kg  = t & 15;
  int row = t >> 4;
  #pragma unroll
  for (int p=0;p<4;++p) {
    int r = row + 16*p;
    int i = i0 + r;
    float4 v = make_float4(0.f,0.f,0.f,0.f);
    if (i < M) v = *(const float4*)(G + (size_t)i*64 + 4*kg);
    Gi[4*kg+0][r]=v.x; Gi[4*kg+1][r]=v.y; Gi[4*kg+2][r]=v.z; Gi[4*kg+3][r]=v.w;
    int j = j0 + jt0 + r;
    float4 w = make_float4(0.f,0.f,0.f,0.f);
    if (j < M) w = *(const float4*)(G + (size_t)j*64 + 4*kg);
    Gj[4*kg+0][r]=w.x; Gj[4*kg+1][r]=w.y; Gj[4*kg+2][r]=w.z; Gj[4*kg+3][r]=w.w;
  }
  __syncthreads();
  float acc[4][4] = {};
  #pragma unroll 8
  for (int kk=0;kk<64;++kk) {
    float4 a = *(const float4*)&Gi[kk][ty*4];
    float4 b = *(const float4*)&Gj[kk][tx*4];
    float av[4]={a.x,a.y,a.z,a.w};
    float bv[4]={b.x,b.y,b.z,b.w};
    #pragma unroll
    for (int i=0;i<4;++i)
      #pragma unroll
      for (int j=0;j<4;++j) acc[i][j] += av[i]*bv[j];
  }
  #pragma unroll
  for (int i=0;i<4;++i){
    int ii = i0 + ty*4 + i;
    if (ii >= M) continue;
    #pragma unroll
    for (int j=0;j<4;++j){
      int jl = jt0 + tx*4 + j;
      int jg = j0 + jl;
      if (jl < JB && jg < M)
        slab[(size_t)ii*JB + jl] = 2.f*acc[i][j] - sqv[ii] - sqv[jg];
    }
  }
}

// ---------------- per-row top-50 via 4-pass radix select over mapped keys ------
// keys: monotone map of fp32 (sign? ~u : u|0x80000000); larger key == larger float.
// Finds exact key T of the 50th largest, takes all keys>T plus the `r` smallest-
// index ties ==T (matches jax.lax.top_k's lower-index tie-break as a set).
__global__ __launch_bounds__(256) void topk_select(
    const float* __restrict__ slab, int j0, int jcount,
    unsigned int* __restrict__ topk, int* __restrict__ topi, int M)
{
  __shared__ unsigned int keys[JB + KNN];
  __shared__ int hist[256];
  __shared__ int red2[256];
  __shared__ int oldidx[KNN];
  __shared__ int outidx[KNN];
  __shared__ unsigned int outkey[KNN];
  __shared__ int b_star, cnt;
  int i = blockIdx.x, t = threadIdx.x;
  for (int p=t; p<jcount; p+=256) {
    unsigned u = __float_as_uint(slab[(size_t)i*JB + p]);
    keys[p] = (u & 0x80000000u) ? ~u : (u | 0x80000000u);
  }
  for (int p=jcount+t; p<JB; p+=256) keys[p] = 0u;
  if (t < KNN) { keys[JB+t] = topk[(size_t)i*KNN+t]; oldidx[t] = topi[(size_t)i*KNN+t]; }
  if (t == 0) cnt = 0;
  __syncthreads();
  const int total = JB + KNN;
  unsigned prefix = 0, pmask = 0;
  int need = KNN;
  #pragma unroll
  for (int pass=0; pass<4; ++pass) {
    int shift = 24 - 8*pass;
    hist[t] = 0; __syncthreads();
    for (int p=t; p<total; p+=256) {
      unsigned k = keys[p];
      if ((k & pmask) == prefix) atomicAdd(&hist[(k>>shift)&255], 1);
    }
    __syncthreads();
    // inclusive suffix sum (Hillis-Steele)
    for (int off=1; off<256; off<<=1) {
      int v = (t+off<256) ? hist[t+off] : 0;
      __syncthreads();
      hist[t] += v;
      __syncthreads();
    }
    // b* = max b with S(b) >= need (suffix sums are non-increasing; unique)
    if (hist[t] >= need && (t==255 || hist[t+1] < need)) b_star = t;
    __syncthreads();
    int b = b_star;
    need -= (b < 255) ? hist[b+1] : 0;
    prefix |= ((unsigned)b) << shift;
    pmask  |= 0xFFu << shift;
    __syncthreads();
  }
  // definite members: key > prefix (exactly KNN-need of them)
  for (int p=t; p<total; p+=256) {
    unsigned k = keys[p];
    if (k > prefix) {
      int pos = atomicAdd(&cnt, 1);
      outidx[pos] = (p < JB) ? (j0 + p) : oldidx[p-JB];
      outkey[pos] = k;
    }
  }
  __syncthreads();
  int base = cnt;   // == KNN - need
  // ties: `need` smallest indices with key == prefix, ascending
  int last = -1;
  for (int it=0; it<need; ++it) {
    int best = 0x7fffffff;
    for (int p=t; p<total; p+=256) {
      if (keys[p] == prefix) {
        int idx = (p < JB) ? (j0 + p) : oldidx[p-JB];
        if (idx > last && idx < best) best = idx;
      }
    }
    red2[t] = best; __syncthreads();
    for (int s=128;s>0;s>>=1){ if (t<s) red2[t] = min(red2[t], red2[t+s]); __syncthreads(); }
    if (t==0) { outidx[base+it] = red2[0]; outkey[base+it] = prefix; }
    last = red2[0];
    __syncthreads();
  }
  if (t < KNN) { topk[(size_t)i*KNN+t] = outkey[t]; topi[(size_t)i*KNN+t] = outidx[t]; }
}

// ---------------- gather-mean over top-50 + LayerNorm, writes cat[:,256:512] ----
__global__ __launch_bounds__(256) void knn_mean_ln(
    float* __restrict__ cat, const int* __restrict__ topi,
    const float* __restrict__ g, const float* __restrict__ b, int M)
{
  int i = blockIdx.x; int t = threadIdx.x;
  __shared__ int idx[KNN];
  __shared__ float red[256];
  if (t<KNN) idx[t]=topi[(size_t)i*KNN+t];
  __syncthreads();
  float acc=0.f;
  for (int r=0;r<KNN;++r) acc += cat[(size_t)idx[r]*512 + t];
  float xval = acc * (1.f/KNN);
  red[t]=xval; __syncthreads();
  for (int s=128;s>0;s>>=1){ if(t<s) red[t]+=red[t+s]; __syncthreads(); }
  float mu = red[0]*(1.f/256.f); __syncthreads();
  float d = xval-mu;
  red[t]=d*d; __syncthreads();
  for (int s=128;s>0;s>>=1){ if(t<s) red[t]+=red[t+s]; __syncthreads(); }
  float var = red[0]*(1.f/256.f);
  float y = d * rsqrtf(var+1e-5f) * g[t] + b[t];
  cat[(size_t)i*512 + 256 + t] = y;
}

// ================================================================
extern "C" void kernel_launch(void* const* d_in, const int* in_sizes, int n_in,
                              void* d_out, int out_size, void* d_ws, size_t ws_size,
                              hipStream_t stream)
{
  const float* x      = (const float*)d_in[0];
  const int*   ei     = (const int*)  d_in[1];
  const float* lin1_w = (const float*)d_in[2];
  const float* lin1_b = (const float*)d_in[3];
  const float* gat1_w = (const float*)d_in[4];
  const float* g1_as  = (const float*)d_in[5];
  const float* g1_ad  = (const float*)d_in[6];
  const float* gat1_b = (const float*)d_in[7];
  const float* gat2_w = (const float*)d_in[8];
  const float* g2_as  = (const float*)d_in[9];
  const float* g2_ad  = (const float*)d_in[10];
  const float* gat2_b = (const float*)d_in[11];
  const float* proj_w = (const float*)d_in[12];
  const float* proj_b = (const float*)d_in[13];
  const float* ln_g   = (const float*)d_in[14];
  const float* ln_b   = (const float*)d_in[15];
  const float* lin_w  = (const float*)d_in[16];
  const float* lin_b  = (const float*)d_in[17];
  float* outp = (float*)d_out;

  const int N = in_sizes[0]/FIN;    // 10000
  const int E = in_sizes[1]/2;      // 320000
  const int* srcv = ei;
  const int* dstv = ei + E;

  float* ws = (float*)d_ws;
  size_t f = 0;
  float* h1   = ws + f; f += (size_t)N*1024;
  float* xg   = ws + f; f += (size_t)N*1024;
  float* slab = h1;                       // overlays h1+xg (dead by knn time)
  float* cat  = ws + f; f += (size_t)N*512;
  float* al1s = ws + f; f += (size_t)N*8;
  float* al1d = ws + f; f += (size_t)N*8;
  float* h2   = ws + f; f += (size_t)N*128;
  float* al2s = ws + f; f += (size_t)N;
  float* al2d = ws + f; f += (size_t)N;
  float* gsc  = ws + f; f += (size_t)N*64;
  float* sqv  = ws + f; f += (size_t)N;
  unsigned int* topk = (unsigned int*)(ws + f); f += (size_t)N*KNN;
  int* topi   = (int*)(ws + f); f += (size_t)N*KNN;
  int* deg    = (int*)(ws + f); f += (size_t)N;
  int* offs   = (int*)(ws + f); f += (size_t)N;
  int* cursor = (int*)(ws + f); f += (size_t)N;
  int* csr    = (int*)(ws + f); f += (size_t)E;
  (void)ws_size; (void)n_in; (void)out_size;

  dim3 b256(256);
  int gy = (N+63)/64;

  // CSR by dst
  k_zero_int<<<(N+255)/256, b256, 0, stream>>>(deg, N);
  k_count_deg<<<(E+255)/256, b256, 0, stream>>>(dstv, deg, E);
  k_scan<<<1, b256, 0, stream>>>(deg, offs, cursor, N);
  k_fill_csr<<<(E+255)/256, b256, 0, stream>>>(dstv, cursor, csr, E);
  k_sort_csr<<<(N+255)/256, b256, 0, stream>>>(csr, offs, deg, N);

  // x1 = relu(x@lin1_w.T + b) -> cat[:, :128]
  gemm_bt<<<dim3(2,gy), b256, 0, stream>>>(x,FIN, lin1_w,FIN, lin1_b, cat,512,0, N,FIN,128, 1);
  // h1 = x @ gat1_w.T
  gemm_bt<<<dim3(16,gy), b256, 0, stream>>>(x,FIN, gat1_w,FIN, nullptr, h1,1024,0, N,FIN,1024, 0);
  att_logits<<<(N*8+255)/256, b256, 0, stream>>>(h1, g1_as, g1_ad, al1s, al1d, 8, N);
  gat_aggregate<8,1024,1><<<N, b256, 0, stream>>>(h1, al1s, al1d, csr, offs, deg, srcv, gat1_b, xg,1024,0, N);
  // h2 = xg @ gat2_w.T
  gemm_bt<<<dim3(2,gy), b256, 0, stream>>>(xg,1024, gat2_w,1024, nullptr, h2,128,0, N,1024,128, 0);
  att_logits<<<(N+255)/256, b256, 0, stream>>>(h2, g2_as, g2_ad, al2s, al2d, 1, N);
  gat_aggregate<1,128,0><<<N, b256, 0, stream>>>(h2, al2s, al2d, csr, offs, deg, srcv, gat2_b, cat,512,128, N);
  // g_score = final @ proj_w.T + proj_b
  gemm_bt<<<dim3(1,gy), b256, 0, stream>>>(cat,512, proj_w,256, proj_b, gsc,64,0, N,256,64, 0);
  k_sq<<<(N+255)/256, b256, 0, stream>>>(gsc, sqv, N);
  k_init_topk<<<(N*KNN+255)/256, b256, 0, stream>>>(topk, topi, N*KNN);
  // knn: 5 slabs of 2000 columns; gram then radix-select top-50 merge
  for (int j0=0; j0<N; j0+=JB){
    int jc = (N - j0 < JB) ? (N - j0) : JB;
    gram_negd2<<<dim3((JB+63)/64, gy), b256, 0, stream>>>(gsc, sqv, slab, j0, N);
    topk_select<<<N, b256, 0, stream>>>(slab, j0, jc, topk, topi, N);
  }
  knn_mean_ln<<<N, b256, 0, stream>>>(cat, topi, ln_g, ln_b, N);
  // out = [final, sim] @ lin_w.T + lin_b
  gemm_bt<<<dim3(1,gy), b256, 0, stream>>>(cat,512, lin_w,512, lin_b, outp,64,0, N,512,64, 0);
}

// Round 3
// 1621.980 us; speedup vs baseline: 3.4358x; 1.0668x over previous
//
#include <hip/hip_runtime.h>

#define FIN 256
#define KNN 50
#define JB  2000

static __device__ __forceinline__ float lrelu02(float v){ return v > 0.f ? v : 0.2f*v; }

// ---------------- CSR construction ----------------
__global__ __launch_bounds__(256) void k_zero_int(int* p, int n){
  int i = blockIdx.x*256 + threadIdx.x; if (i<n) p[i]=0;
}
__global__ __launch_bounds__(256) void k_count_deg(const int* __restrict__ dstv, int* deg, int E){
  int i = blockIdx.x*256 + threadIdx.x; if (i<E) atomicAdd(&deg[dstv[i]], 1);
}
__global__ __launch_bounds__(256) void k_scan(const int* __restrict__ deg, int* offs, int* cursor, int n){
  __shared__ int buf[256]; __shared__ int carry;
  int t = threadIdx.x;
  if (t==0) carry = 0;
  __syncthreads();
  for (int base=0; base<n; base+=256){
    int v = (base+t<n)? deg[base+t] : 0;
    buf[t]=v; __syncthreads();
    for (int off=1; off<256; off<<=1){
      int add = (t>=off)? buf[t-off] : 0;
      __syncthreads();
      buf[t]+=add; __syncthreads();
    }
    int excl = buf[t]-v+carry;
    if (base+t<n){ offs[base+t]=excl; cursor[base+t]=excl; }
    __syncthreads();
    if (t==0) carry += buf[255];
    __syncthreads();
  }
}
__global__ __launch_bounds__(256) void k_fill_csr(const int* __restrict__ dstv, int* cursor, int* csr, int E){
  int i = blockIdx.x*256 + threadIdx.x;
  if (i<E){ int p=atomicAdd(&cursor[dstv[i]],1); csr[p]=i; }
}
// deterministic aggregation order: sort each node's edge list ascending by edge id
__global__ __launch_bounds__(256) void k_sort_csr(int* csr, const int* __restrict__ offs, const int* __restrict__ deg, int n){
  int i = blockIdx.x*256+threadIdx.x; if (i>=n) return;
  int st=offs[i], d=deg[i];
  for (int a=0;a<d-1;++a){
    int mv=csr[st+a], mp=a;
    for (int b=a+1;b<d;++b){ int v=csr[st+b]; if (v<mv){mv=v;mp=b;} }
    int tmp=csr[st+a]; csr[st+a]=mv; csr[st+mp]=tmp;
  }
}

// ---------------- fold attention vectors into weights ----------------
// Wf[o][k] (o<8: src head o, o>=8: dst head o-8) = sum_c a[h][c] * W1[h*128+c][k]
__global__ __launch_bounds__(256) void k_fold(
  const float* __restrict__ W, const float* __restrict__ as8, const float* __restrict__ ad8,
  float* __restrict__ Wf)
{
  int o = blockIdx.x;       // 0..15
  int t = threadIdx.x;      // k = 0..255
  int h = o & 7;
  const float* av = (o<8) ? (as8 + h*128) : (ad8 + h*128);
  const float* wp = W + (size_t)h*128*256 + t;
  float acc = 0.f;
  #pragma unroll 4
  for (int c=0;c<128;++c) acc += av[c] * wp[(size_t)c*256];
  Wf[o*256+t] = acc;
}

// ---------------- generic fp32 GEMM: C = act(A * W^T + b), z-batched ----------------
__global__ __launch_bounds__(256) void gemm_bt(
    const float* __restrict__ A, int lda,
    const float* __restrict__ W, int ldw,
    const float* __restrict__ bias,
    float* __restrict__ C, int ldc, int coff,
    int M, int Kdim, int O, int relu,
    int az, int wz, int cz, int bz)
{
  A += (size_t)blockIdx.z * az;
  W += (size_t)blockIdx.z * wz;
  if (bias) bias += (size_t)blockIdx.z * bz;
  coff += blockIdx.z * cz;
  __shared__ float As[32][68];
  __shared__ float Ws[32][68];
  int t  = threadIdx.x;
  int n0 = blockIdx.y * 64;
  int o0 = blockIdx.x * 64;
  int tx = t & 15, ty = t >> 4;
  float acc[4][4] = {};
  int kgrp = t & 7;      // k = 4*kgrp
  int row  = t >> 3;     // 0..31
  for (int k0 = 0; k0 < Kdim; k0 += 32) {
    #pragma unroll
    for (int p = 0; p < 2; ++p) {
      int r = row + 32*p;
      int n = n0 + r;
      float4 v = make_float4(0.f,0.f,0.f,0.f);
      if (n < M) v = *(const float4*)(A + (size_t)n*lda + k0 + 4*kgrp);
      As[4*kgrp+0][r] = v.x; As[4*kgrp+1][r] = v.y;
      As[4*kgrp+2][r] = v.z; As[4*kgrp+3][r] = v.w;
      int o = o0 + r;
      float4 w = make_float4(0.f,0.f,0.f,0.f);
      if (o < O) w = *(const float4*)(W + (size_t)o*ldw + k0 + 4*kgrp);
      Ws[4*kgrp+0][r] = w.x; Ws[4*kgrp+1][r] = w.y;
      Ws[4*kgrp+2][r] = w.z; Ws[4*kgrp+3][r] = w.w;
    }
    __syncthreads();
    #pragma unroll 8
    for (int kk = 0; kk < 32; ++kk) {
      float4 a = *(const float4*)&As[kk][ty*4];
      float4 w = *(const float4*)&Ws[kk][tx*4];
      float av[4] = {a.x,a.y,a.z,a.w};
      float wv[4] = {w.x,w.y,w.z,w.w};
      #pragma unroll
      for (int i=0;i<4;++i)
        #pragma unroll
        for (int j=0;j<4;++j) acc[i][j] += av[i]*wv[j];
    }
    __syncthreads();
  }
  #pragma unroll
  for (int i=0;i<4;++i) {
    int n = n0 + ty*4 + i;
    if (n >= M) continue;
    #pragma unroll
    for (int j=0;j<4;++j) {
      int o = o0 + tx*4 + j;
      if (o >= O) continue;
      float v = acc[i][j] + (bias ? bias[o] : 0.f);
      if (relu) v = fmaxf(v, 0.f);
      C[(size_t)n*ldc + coff + o] = v;
    }
  }
}

// ---------------- attention logits (gat2, H=1) ----------------
__global__ __launch_bounds__(256) void att_logits(
    const float* __restrict__ hbuf, const float* __restrict__ asrc,
    const float* __restrict__ adst, float* __restrict__ als, float* __restrict__ ald,
    int H, int M)
{
  int gidx = blockIdx.x*256 + threadIdx.x;
  if (gidx >= M*H) return;
  int n = gidx / H, h = gidx % H;
  const float* hp = hbuf + (size_t)n*H*128 + (size_t)h*128;
  const float* as = asrc + h*128;
  const float* ad = adst + h*128;
  float s1=0.f, s2=0.f;
  for (int c=0;c<128;++c){ float v=hp[c]; s1 += v*as[c]; s2 += v*ad[c]; }
  als[gidx]=s1; ald[gidx]=s2;
}

// ---------------- gat1: input-space softmax aggregation ----------------
// agg[n, h, :] = sum_e alpha[e, h0+h] * x[src_e, :]   (NH heads per pass)
// al1 layout: [N,16]  cols 0..7 = src logits, 8..15 = dst logits
template<int NH>
__global__ __launch_bounds__(256) void gat1_agg_x(
    const float* __restrict__ x, const float* __restrict__ al1,
    const int* __restrict__ csr, const int* __restrict__ offs, const int* __restrict__ deg,
    const int* __restrict__ srcv,
    float* __restrict__ agg, int h0, int M)
{
  const int n = blockIdx.x, t = threadIdx.x;
  const int d = deg[n], st = offs[n];
  const int lane = t & 63, w = t >> 6;
  __shared__ float sh_ald[NH];
  __shared__ float wpart[4*NH];
  __shared__ float emax_s[NH], den_s[NH];
  __shared__ int   s_lds[128];
  __shared__ float alpha_lds[128*NH];
  if (t < NH) sh_ald[t] = al1[(size_t)n*16 + 8 + h0 + t];
  __syncthreads();
  // ---- phase A: per-head max of leaky_relu(al_src[s]+al_dst[n])
  float lm[NH];
  #pragma unroll
  for (int h=0;h<NH;++h) lm[h] = -__builtin_inff();
  for (int q=t; q<d; q+=256) {
    int s = srcv[csr[st+q]];
    float av[NH];
    float4 a0 = *(const float4*)(al1 + (size_t)s*16 + h0);
    av[0]=a0.x; av[1]=a0.y; av[2]=a0.z; av[3]=a0.w;
    if constexpr (NH==8){
      float4 a1 = *(const float4*)(al1 + (size_t)s*16 + h0 + 4);
      av[4]=a1.x; av[5]=a1.y; av[6]=a1.z; av[7]=a1.w;
    }
    #pragma unroll
    for (int h=0;h<NH;++h) lm[h] = fmaxf(lm[h], lrelu02(av[h] + sh_ald[h]));
  }
  #pragma unroll
  for (int h=0;h<NH;++h){
    float v = lm[h];
    for (int off=32;off>0;off>>=1) v = fmaxf(v, __shfl_down(v, off, 64));
    if (lane==0) wpart[w*NH+h] = v;
  }
  __syncthreads();
  if (t < NH)
    emax_s[t] = fmaxf(fmaxf(wpart[t], wpart[NH+t]), fmaxf(wpart[2*NH+t], wpart[3*NH+t]));
  __syncthreads();
  // ---- phase B: denom = sum exp(e - emax) + 1e-16
  float ls[NH];
  #pragma unroll
  for (int h=0;h<NH;++h) ls[h]=0.f;
  for (int q=t; q<d; q+=256) {
    int s = srcv[csr[st+q]];
    float av[NH];
    float4 a0 = *(const float4*)(al1 + (size_t)s*16 + h0);
    av[0]=a0.x; av[1]=a0.y; av[2]=a0.z; av[3]=a0.w;
    if constexpr (NH==8){
      float4 a1 = *(const float4*)(al1 + (size_t)s*16 + h0 + 4);
      av[4]=a1.x; av[5]=a1.y; av[6]=a1.z; av[7]=a1.w;
    }
    #pragma unroll
    for (int h=0;h<NH;++h) ls[h] += expf(lrelu02(av[h] + sh_ald[h]) - emax_s[h]);
  }
  #pragma unroll
  for (int h=0;h<NH;++h){
    float v = ls[h];
    for (int off=32;off>0;off>>=1) v += __shfl_down(v, off, 64);
    if (lane==0) wpart[w*NH+h] = v;
  }
  __syncthreads();
  if (t < NH)
    den_s[t] = wpart[t] + wpart[NH+t] + wpart[2*NH+t] + wpart[3*NH+t] + 1e-16f;
  // ---- phase C: chunked alpha + coalesced x-row accumulation
  float acc[NH];
  #pragma unroll
  for (int h=0;h<NH;++h) acc[h]=0.f;
  for (int c0=0; c0<d; c0+=128) {
    int cl = min(128, d-c0);
    __syncthreads();
    for (int q=t; q<cl; q+=256) s_lds[q] = srcv[csr[st+c0+q]];
    __syncthreads();
    for (int idx=t; idx<cl*NH; idx+=256) {
      int q = idx / NH, h = idx % NH;
      float als = al1[(size_t)s_lds[q]*16 + h0 + h];
      float v = lrelu02(als + sh_ald[h]);
      alpha_lds[q*NH+h] = expf(v - emax_s[h]) / den_s[h];
    }
    __syncthreads();
    for (int q=0; q<cl; ++q) {
      float xv = x[(size_t)s_lds[q]*FIN + t];
      #pragma unroll
      for (int h=0;h<NH;++h) acc[h] += alpha_lds[q*NH+h] * xv;
    }
  }
  #pragma unroll
  for (int h=0;h<NH;++h) agg[(size_t)n*(NH*256) + h*256 + t] = acc[h];
}

// ---------------- GAT softmax-aggregation in output space (gat2, H=1) -----
template<int H, int OUT, int RELU>
__global__ __launch_bounds__(256) void gat_aggregate(
  const float* __restrict__ hbuf, const float* __restrict__ als, const float* __restrict__ ald,
  const int* __restrict__ csr, const int* __restrict__ offs, const int* __restrict__ deg,
  const int* __restrict__ srcv, const float* __restrict__ bias,
  float* __restrict__ outp, int ldo, int coff, int M)
{
  int n = blockIdx.x; int t = threadIdx.x;
  int d = deg[n], st = offs[n];
  __shared__ float red[256];
  __shared__ float emax[H], dsum[H];
  float lm[H];
  #pragma unroll
  for (int h=0;h<H;++h) lm[h] = -__builtin_inff();
  for (int q=t;q<d;q+=256) {
    int eid = csr[st+q]; int s = srcv[eid];
    #pragma unroll
    for (int h=0;h<H;++h) {
      float v = lrelu02(als[s*H+h] + ald[n*H+h]);
      lm[h] = fmaxf(lm[h], v);
    }
  }
  #pragma unroll
  for (int h=0;h<H;++h) {
    red[t]=lm[h]; __syncthreads();
    for (int s2=128;s2>0;s2>>=1){ if(t<s2) red[t]=fmaxf(red[t],red[t+s2]); __syncthreads(); }
    if (t==0) emax[h]=red[0];
    __syncthreads();
  }
  float ls[H];
  #pragma unroll
  for (int h=0;h<H;++h) ls[h]=0.f;
  for (int q=t;q<d;q+=256) {
    int eid = csr[st+q]; int s = srcv[eid];
    #pragma unroll
    for (int h=0;h<H;++h) {
      float v = lrelu02(als[s*H+h] + ald[n*H+h]);
      ls[h] += expf(v - emax[h]);
    }
  }
  #pragma unroll
  for (int h=0;h<H;++h) {
    red[t]=ls[h]; __syncthreads();
    for (int s2=128;s2>0;s2>>=1){ if(t<s2) red[t]+=red[t+s2]; __syncthreads(); }
    if (t==0) dsum[h]=red[0] + 1e-16f;
    __syncthreads();
  }
  int base = t*4;
  if (base < OUT) {
    const int h = base >> 7;
    float a0=0.f,a1=0.f,a2=0.f,a3=0.f;
    float em = emax[h], dn = dsum[h];
    float aldnh = ald[n*H+h];
    for (int q=0;q<d;++q) {
      int eid=csr[st+q]; int s=srcv[eid];
      float v = lrelu02(als[s*H+h] + aldnh);
      float alpha = expf(v-em)/dn;
      float4 hv = *(const float4*)(hbuf + (size_t)s*OUT + base);
      a0 += hv.x*alpha; a1 += hv.y*alpha; a2 += hv.z*alpha; a3 += hv.w*alpha;
    }
    a0 += bias[base+0]; a1 += bias[base+1]; a2 += bias[base+2]; a3 += bias[base+3];
    if (RELU){ a0=fmaxf(a0,0.f); a1=fmaxf(a1,0.f); a2=fmaxf(a2,0.f); a3=fmaxf(a3,0.f); }
    float* op = outp + (size_t)n*ldo + coff + base;
    op[0]=a0; op[1]=a1; op[2]=a2; op[3]=a3;
  }
}

// ---------------- knn: sq norms ----------------
__global__ __launch_bounds__(256) void k_sq(const float* __restrict__ g, float* sq, int n){
  int i = blockIdx.x*256+threadIdx.x;
  if (i<n){ const float* p=g+(size_t)i*64; float s=0.f; for(int c=0;c<64;++c) s+=p[c]*p[c]; sq[i]=s; }
}
__global__ __launch_bounds__(256) void k_init_topk(unsigned int* tk, int* ti, int n){
  int i = blockIdx.x*256+threadIdx.x;
  if (i<n){ tk[i]=0u; ti[i]=0x7fffffff; }
}

// ---------------- gram slab: neg_d2 = 2*(g_i . g_j) - sq_i - sq_j ----------------
__global__ __launch_bounds__(256) void gram_negd2(
    const float* __restrict__ G, const float* __restrict__ sqv,
    float* __restrict__ slab, int j0, int M)
{
  __shared__ float Gi[64][68];
  __shared__ float Gj[64][68];
  int t = threadIdx.x;
  int i0  = blockIdx.y * 64;
  int jt0 = blockIdx.x * 64;
  int tx = t & 15, ty = t >> 4;
  int kg  = t & 15;
  int row = t >> 4;
  #pragma unroll
  for (int p=0;p<4;++p) {
    int r = row + 16*p;
    int i = i0 + r;
    float4 v = make_float4(0.f,0.f,0.f,0.f);
    if (i < M) v = *(const float4*)(G + (size_t)i*64 + 4*kg);
    Gi[4*kg+0][r]=v.x; Gi[4*kg+1][r]=v.y; Gi[4*kg+2][r]=v.z; Gi[4*kg+3][r]=v.w;
    int j = j0 + jt0 + r;
    float4 w = make_float4(0.f,0.f,0.f,0.f);
    if (j < M) w = *(const float4*)(G + (size_t)j*64 + 4*kg);
    Gj[4*kg+0][r]=w.x; Gj[4*kg+1][r]=w.y; Gj[4*kg+2][r]=w.z; Gj[4*kg+3][r]=w.w;
  }
  __syncthreads();
  float acc[4][4] = {};
  #pragma unroll 8
  for (int kk=0;kk<64;++kk) {
    float4 a = *(const float4*)&Gi[kk][ty*4];
    float4 b = *(const float4*)&Gj[kk][tx*4];
    float av[4]={a.x,a.y,a.z,a.w};
    float bv[4]={b.x,b.y,b.z,b.w};
    #pragma unroll
    for (int i=0;i<4;++i)
      #pragma unroll
      for (int j=0;j<4;++j) acc[i][j] += av[i]*bv[j];
  }
  #pragma unroll
  for (int i=0;i<4;++i){
    int ii = i0 + ty*4 + i;
    if (ii >= M) continue;
    #pragma unroll
    for (int j=0;j<4;++j){
      int jl = jt0 + tx*4 + j;
      int jg = j0 + jl;
      if (jl < JB && jg < M)
        slab[(size_t)ii*JB + jl] = 2.f*acc[i][j] - sqv[ii] - sqv[jg];
    }
  }
}

// ---------------- per-row top-50 via 4-pass radix select over mapped keys ------
__global__ __launch_bounds__(256) void topk_select(
    const float* __restrict__ slab, int j0, int jcount,
    unsigned int* __restrict__ topk, int* __restrict__ topi, int M)
{
  __shared__ unsigned int keys[JB + KNN];
  __shared__ int hist[256];
  __shared__ int red2[256];
  __shared__ int oldidx[KNN];
  __shared__ int outidx[KNN];
  __shared__ unsigned int outkey[KNN];
  __shared__ int b_star, cnt;
  int i = blockIdx.x, t = threadIdx.x;
  for (int p=t; p<jcount; p+=256) {
    unsigned u = __float_as_uint(slab[(size_t)i*JB + p]);
    keys[p] = (u & 0x80000000u) ? ~u : (u | 0x80000000u);
  }
  for (int p=jcount+t; p<JB; p+=256) keys[p] = 0u;
  if (t < KNN) { keys[JB+t] = topk[(size_t)i*KNN+t]; oldidx[t] = topi[(size_t)i*KNN+t]; }
  if (t == 0) cnt = 0;
  __syncthreads();
  const int total = JB + KNN;
  unsigned prefix = 0, pmask = 0;
  int need = KNN;
  #pragma unroll
  for (int pass=0; pass<4; ++pass) {
    int shift = 24 - 8*pass;
    hist[t] = 0; __syncthreads();
    for (int p=t; p<total; p+=256) {
      unsigned k = keys[p];
      if ((k & pmask) == prefix) atomicAdd(&hist[(k>>shift)&255], 1);
    }
    __syncthreads();
    for (int off=1; off<256; off<<=1) {
      int v = (t+off<256) ? hist[t+off] : 0;
      __syncthreads();
      hist[t] += v;
      __syncthreads();
    }
    if (hist[t] >= need && (t==255 || hist[t+1] < need)) b_star = t;
    __syncthreads();
    int b = b_star;
    need -= (b < 255) ? hist[b+1] : 0;
    prefix |= ((unsigned)b) << shift;
    pmask  |= 0xFFu << shift;
    __syncthreads();
  }
  for (int p=t; p<total; p+=256) {
    unsigned k = keys[p];
    if (k > prefix) {
      int pos = atomicAdd(&cnt, 1);
      outidx[pos] = (p < JB) ? (j0 + p) : oldidx[p-JB];
      outkey[pos] = k;
    }
  }
  __syncthreads();
  int base = cnt;
  int last = -1;
  for (int it=0; it<need; ++it) {
    int best = 0x7fffffff;
    for (int p=t; p<total; p+=256) {
      if (keys[p] == prefix) {
        int idx = (p < JB) ? (j0 + p) : oldidx[p-JB];
        if (idx > last && idx < best) best = idx;
      }
    }
    red2[t] = best; __syncthreads();
    for (int s=128;s>0;s>>=1){ if (t<s) red2[t] = min(red2[t], red2[t+s]); __syncthreads(); }
    if (t==0) { outidx[base+it] = red2[0]; outkey[base+it] = prefix; }
    last = red2[0];
    __syncthreads();
  }
  if (t < KNN) { topk[(size_t)i*KNN+t] = outkey[t]; topi[(size_t)i*KNN+t] = outidx[t]; }
}

// ---------------- gather-mean over top-50 + LayerNorm, writes cat[:,256:512] ----
__global__ __launch_bounds__(256) void knn_mean_ln(
    float* __restrict__ cat, const int* __restrict__ topi,
    const float* __restrict__ g, const float* __restrict__ b, int M)
{
  int i = blockIdx.x; int t = threadIdx.x;
  __shared__ int idx[KNN];
  __shared__ float red[256];
  if (t<KNN) idx[t]=topi[(size_t)i*KNN+t];
  __syncthreads();
  float acc=0.f;
  for (int r=0;r<KNN;++r) acc += cat[(size_t)idx[r]*512 + t];
  float xval = acc * (1.f/KNN);
  red[t]=xval; __syncthreads();
  for (int s=128;s>0;s>>=1){ if(t<s) red[t]+=red[t+s]; __syncthreads(); }
  float mu = red[0]*(1.f/256.f); __syncthreads();
  float d = xval-mu;
  red[t]=d*d; __syncthreads();
  for (int s=128;s>0;s>>=1){ if(t<s) red[t]+=red[t+s]; __syncthreads(); }
  float var = red[0]*(1.f/256.f);
  float y = d * rsqrtf(var+1e-5f) * g[t] + b[t];
  cat[(size_t)i*512 + 256 + t] = y;
}

// ================================================================
extern "C" void kernel_launch(void* const* d_in, const int* in_sizes, int n_in,
                              void* d_out, int out_size, void* d_ws, size_t ws_size,
                              hipStream_t stream)
{
  const float* x      = (const float*)d_in[0];
  const int*   ei     = (const int*)  d_in[1];
  const float* lin1_w = (const float*)d_in[2];
  const float* lin1_b = (const float*)d_in[3];
  const float* gat1_w = (const float*)d_in[4];
  const float* g1_as  = (const float*)d_in[5];
  const float* g1_ad  = (const float*)d_in[6];
  const float* gat1_b = (const float*)d_in[7];
  const float* gat2_w = (const float*)d_in[8];
  const float* g2_as  = (const float*)d_in[9];
  const float* g2_ad  = (const float*)d_in[10];
  const float* gat2_b = (const float*)d_in[11];
  const float* proj_w = (const float*)d_in[12];
  const float* proj_b = (const float*)d_in[13];
  const float* ln_g   = (const float*)d_in[14];
  const float* ln_b   = (const float*)d_in[15];
  const float* lin_w  = (const float*)d_in[16];
  const float* lin_b  = (const float*)d_in[17];
  float* outp = (float*)d_out;

  const int N = in_sizes[0]/FIN;    // 10000
  const int E = in_sizes[1]/2;      // 320000
  const int* srcv = ei;
  const int* dstv = ei + E;

  // ws layout: [agg][xg][cat][al1][h2][al2s][al2d][gsc][sqv][topk][topi][deg][offs][cursor][csr][Wf]
  // full mode: agg = N*2048 (8 heads, one pass). fallback: agg = N*1024 (2 passes of 4 heads).
  size_t needFull = sizeof(float)*((size_t)N*(2048+1024+512+16+128+1+1+64+1+50+50+1+1+1) + E + 4096);
  bool full = ws_size >= needFull;
  size_t aggF = full ? (size_t)N*2048 : (size_t)N*1024;

  float* ws = (float*)d_ws;
  size_t f = 0;
  float* agg  = ws + f; f += aggF;
  float* xg   = ws + f; f += (size_t)N*1024;
  float* slab = agg;                      // overlays agg(+xg in split mode); dead by knn time
  float* cat  = ws + f; f += (size_t)N*512;
  float* al1  = ws + f; f += (size_t)N*16;
  float* h2   = ws + f; f += (size_t)N*128;
  float* al2s = ws + f; f += (size_t)N;
  float* al2d = ws + f; f += (size_t)N;
  float* gsc  = ws + f; f += (size_t)N*64;
  float* sqv  = ws + f; f += (size_t)N;
  unsigned int* topk = (unsigned int*)(ws + f); f += (size_t)N*KNN;
  int* topi   = (int*)(ws + f); f += (size_t)N*KNN;
  int* deg    = (int*)(ws + f); f += (size_t)N;
  int* offs   = (int*)(ws + f); f += (size_t)N;
  int* cursor = (int*)(ws + f); f += (size_t)N;
  int* csr    = (int*)(ws + f); f += (size_t)E;
  float* Wf   = ws + f; f += 4096;
  (void)n_in; (void)out_size;

  dim3 b256(256);
  int gy = (N+63)/64;

  // CSR by dst
  k_zero_int<<<(N+255)/256, b256, 0, stream>>>(deg, N);
  k_count_deg<<<(E+255)/256, b256, 0, stream>>>(dstv, deg, E);
  k_scan<<<1, b256, 0, stream>>>(deg, offs, cursor, N);
  k_fill_csr<<<(E+255)/256, b256, 0, stream>>>(dstv, cursor, csr, E);
  k_sort_csr<<<(N+255)/256, b256, 0, stream>>>(csr, offs, deg, N);

  // fold att vectors into weights; al1 = x @ Wf^T  ([N,16])
  k_fold<<<16, b256, 0, stream>>>(gat1_w, g1_as, g1_ad, Wf);
  gemm_bt<<<dim3(1,gy,1), b256, 0, stream>>>(x,FIN, Wf,FIN, nullptr, al1,16,0, N,FIN,16, 0, 0,0,0,0);

  // x1 = relu(x@lin1_w.T + b) -> cat[:, :128]
  gemm_bt<<<dim3(2,gy,1), b256, 0, stream>>>(x,FIN, lin1_w,FIN, lin1_b, cat,512,0, N,FIN,128, 1, 0,0,0,0);

  // gat1: input-space aggregation, then per-head GEMM -> xg = relu(. + b)
  if (full) {
    gat1_agg_x<8><<<N, b256, 0, stream>>>(x, al1, csr, offs, deg, srcv, agg, 0, N);
    gemm_bt<<<dim3(2,gy,8), b256, 0, stream>>>(agg,2048, gat1_w,FIN, gat1_b, xg,1024,0,
                                               N,FIN,128, 1, 256, 128*256, 128, 128);
  } else {
    for (int h0=0; h0<8; h0+=4) {
      gat1_agg_x<4><<<N, b256, 0, stream>>>(x, al1, csr, offs, deg, srcv, agg, h0, N);
      gemm_bt<<<dim3(2,gy,4), b256, 0, stream>>>(agg,1024, gat1_w + (size_t)h0*128*256,FIN,
                                                 gat1_b + h0*128, xg,1024, h0*128,
                                                 N,FIN,128, 1, 256, 128*256, 128, 128);
    }
  }

  // gat2 (output space, H=1): h2 = xg @ gat2_w.T
  gemm_bt<<<dim3(2,gy,1), b256, 0, stream>>>(xg,1024, gat2_w,1024, nullptr, h2,128,0, N,1024,128, 0, 0,0,0,0);
  att_logits<<<(N+255)/256, b256, 0, stream>>>(h2, g2_as, g2_ad, al2s, al2d, 1, N);
  gat_aggregate<1,128,0><<<N, b256, 0, stream>>>(h2, al2s, al2d, csr, offs, deg, srcv, gat2_b, cat,512,128, N);

  // g_score = final @ proj_w.T + proj_b
  gemm_bt<<<dim3(1,gy,1), b256, 0, stream>>>(cat,512, proj_w,256, proj_b, gsc,64,0, N,256,64, 0, 0,0,0,0);
  k_sq<<<(N+255)/256, b256, 0, stream>>>(gsc, sqv, N);
  k_init_topk<<<(N*KNN+255)/256, b256, 0, stream>>>(topk, topi, N*KNN);
  // knn: 5 slabs of 2000 columns; gram then radix-select top-50 merge
  for (int j0=0; j0<N; j0+=JB){
    int jc = (N - j0 < JB) ? (N - j0) : JB;
    gram_negd2<<<dim3((JB+63)/64, gy), b256, 0, stream>>>(gsc, sqv, slab, j0, N);
    topk_select<<<N, b256, 0, stream>>>(slab, j0, jc, topk, topi, N);
  }
  knn_mean_ln<<<N, b256, 0, stream>>>(cat, topi, ln_g, ln_b, N);
  // out = [final, sim] @ lin_w.T + lin_b
  gemm_bt<<<dim3(1,gy,1), b256, 0, stream>>>(cat,512, lin_w,512, lin_b, outp,64,0, N,512,64, 0, 0,0,0,0);
}